// Round 5
// baseline (946.139 us; speedup 1.0000x reference)
//
#include <hip/hip_runtime.h>
#include <hip/hip_bf16.h>

typedef __bf16 bf16_t;
typedef bf16_t bf16x8 __attribute__((ext_vector_type(8)));
typedef bf16_t bf16x4 __attribute__((ext_vector_type(4)));
typedef float  f32x4  __attribute__((ext_vector_type(4)));

constexpr int kN = 50000;   // nodes
constexpr int kE = 800000;  // edges
constexpr int kD = 128;     // D == H
constexpr int EPAD = 136;   // bf16 LDS row stride (P_lds / t1)
constexpr int ASTR = 132;   // aggbuf LDS row stride (fp32)
constexpr int kCap = 2048;  // per-bucket slot capacity (mean 1024, sd ~45 -> never overflows)
constexpr int NBKT = (kN + 63) / 64;  // 782 buckets == fused blocks
constexpr int BUCKET_BLOCKS = 512;

__device__ __forceinline__ f32x4 mfma16(bf16x8 a, bf16x8 b, f32x4 c) {
  return __builtin_amdgcn_mfma_f32_16x16x32_bf16(a, b, c, 0, 0, 0);
}
__device__ __forceinline__ float silu_f(float x) {
  return x / (1.0f + __expf(-x));
}

// ---------------- K1: weight transposes only ----------------
__global__ void prep_kernel(const float* __restrict__ eW1, const float* __restrict__ eW2,
                            const float* __restrict__ nW1, const float* __restrict__ nW2,
                            bf16_t* __restrict__ W1T, bf16_t* __restrict__ W2T,
                            bf16_t* __restrict__ nW1T, bf16_t* __restrict__ nW2T) {
  const int idx = blockIdx.x * blockDim.x + threadIdx.x;
  const int stride = gridDim.x * blockDim.x;
  for (int i = idx; i < 256 * 128; i += stride) {
    const int n = i >> 8, k = i & 255;  // W1T[n][k] = eW1[k][n]
    W1T[i]  = (bf16_t)eW1[k * 128 + n];
    nW1T[i] = (bf16_t)nW1[k * 128 + n];
  }
  for (int i = idx; i < 128 * 128; i += stride) {
    const int n = i >> 7, k = i & 127;
    W2T[i]  = (bf16_t)eW2[k * 128 + n];
    nW2T[i] = (bf16_t)nW2[k * 128 + n];
  }
}

// ---------------- K2: bucket binning (blocks < BUCKET_BLOCKS) + P/Q + h_bf (rest) ----------------
// P = h@eW1_top + eb1, Q = h@eW1_bot. Slot word = (lrow<<16)|col, lrow = row & 63.
__global__ __launch_bounds__(256, 2) void mega_kernel(
    const float* __restrict__ h, const int* __restrict__ ei,
    const bf16_t* __restrict__ W1T, const float* __restrict__ eb1,
    bf16_t* __restrict__ h_bf, bf16_t* __restrict__ P, bf16_t* __restrict__ Q,
    int* __restrict__ cursor, int* __restrict__ slot_lc) {
  __shared__ bf16_t t1[64 * EPAD];

  if (blockIdx.x < BUCKET_BLOCKS) {
    const int idx = blockIdx.x * blockDim.x + threadIdx.x;
    const int stride = BUCKET_BLOCKS * blockDim.x;
    for (int e = idx; e < kE; e += stride) {
      const int r = ei[e];
      const int c = ei[kE + e];
      const int b = r >> 6;
      const int pos = atomicAdd(&cursor[b * 16], 1);
      if (pos < kCap) slot_lc[b * kCap + pos] = ((r & 63) << 16) | c;
    }
    return;
  }

  const int tid  = threadIdx.x;
  const int wv   = tid >> 6;
  const int lane = tid & 63;
  const int l16  = lane & 15;
  const int quad = lane >> 4;
  const int n0 = wv * 32 + l16;
  const int n1 = n0 + 16;
  const float b1v[2] = {eb1[n0], eb1[n1]};
  const int tb = (blockIdx.x - BUCKET_BLOCKS) * 64;

  f32x4 accp[4][2], accq[4][2];
#pragma unroll
  for (int ms = 0; ms < 4; ++ms)
#pragma unroll
    for (int j = 0; j < 2; ++j) {
      accp[ms][j] = (f32x4){0.f, 0.f, 0.f, 0.f};
      accq[ms][j] = (f32x4){0.f, 0.f, 0.f, 0.f};
    }

#pragma unroll
  for (int ks = 0; ks < 4; ++ks) {
    const bf16_t* wp = W1T + ks * 32 + quad * 8;
    const bf16x8 bt0 = *(const bf16x8*)(wp + (size_t)n0 * 256);
    const bf16x8 bt1 = *(const bf16x8*)(wp + (size_t)n1 * 256);
    const bf16x8 bb0 = *(const bf16x8*)(wp + (size_t)n0 * 256 + 128);
    const bf16x8 bb1 = *(const bf16x8*)(wp + (size_t)n1 * 256 + 128);
#pragma unroll
    for (int ms = 0; ms < 4; ++ms) {
      int node = tb + ms * 16 + l16;
      node = node < kN ? node : kN - 1;
      const float* hp = h + (size_t)node * kD + ks * 32 + quad * 8;
      const float4 f0 = *(const float4*)hp;
      const float4 f1 = *(const float4*)(hp + 4);
      const bf16x8 a = {(bf16_t)f0.x, (bf16_t)f0.y, (bf16_t)f0.z, (bf16_t)f0.w,
                        (bf16_t)f1.x, (bf16_t)f1.y, (bf16_t)f1.z, (bf16_t)f1.w};
      *(bf16x8*)(h_bf + (size_t)node * kD + ks * 32 + quad * 8) = a;  // dup-write benign
      accp[ms][0] = mfma16(a, bt0, accp[ms][0]);
      accp[ms][1] = mfma16(a, bt1, accp[ms][1]);
      accq[ms][0] = mfma16(a, bb0, accq[ms][0]);
      accq[ms][1] = mfma16(a, bb1, accq[ms][1]);
    }
  }

#pragma unroll
  for (int ms = 0; ms < 4; ++ms)
#pragma unroll
    for (int j = 0; j < 2; ++j) {
      const int n = wv * 32 + j * 16 + l16;
#pragma unroll
      for (int r = 0; r < 4; ++r)
        t1[(ms * 16 + quad * 4 + r) * EPAD + n] = (bf16_t)(accp[ms][j][r] + b1v[j]);
    }
  __syncthreads();
  {
    const int row = tid >> 2, cc = (tid & 3) * 32;
    const int node = tb + row;
    if (node < kN) {
#pragma unroll
      for (int u = 0; u < 4; ++u)
        *(bf16x8*)(P + (size_t)node * kD + cc + u * 8) = *(const bf16x8*)&t1[row * EPAD + cc + u * 8];
    }
  }
  __syncthreads();
#pragma unroll
  for (int ms = 0; ms < 4; ++ms)
#pragma unroll
    for (int j = 0; j < 2; ++j) {
      const int n = wv * 32 + j * 16 + l16;
#pragma unroll
      for (int r = 0; r < 4; ++r)
        t1[(ms * 16 + quad * 4 + r) * EPAD + n] = (bf16_t)accq[ms][j][r];
    }
  __syncthreads();
  {
    const int row = tid >> 2, cc = (tid & 3) * 32;
    const int node = tb + row;
    if (node < kN) {
#pragma unroll
      for (int u = 0; u < 4; ++u)
        *(bf16x8*)(Q + (size_t)node * kD + cc + u * 8) = *(const bf16x8*)&t1[row * EPAD + cc + u * 8];
    }
  }
}

// ---------------- K3: fused edge MLP + LDS aggregate + node MLP ----------------
// Block b owns nodes [b*64, b*64+64) and slot bucket b. No global atomics.
__global__ __launch_bounds__(256, 3) void fused_kernel(
    const bf16_t* __restrict__ P, const bf16_t* __restrict__ Q,
    const int* __restrict__ slot_lc, const int* __restrict__ cursor,
    const bf16_t* __restrict__ W2T, const float* __restrict__ eb2,
    const bf16_t* __restrict__ h_bf, const float* __restrict__ h,
    const bf16_t* __restrict__ nW1T, const bf16_t* __restrict__ nW2T,
    const float* __restrict__ nb1, const float* __restrict__ nb2,
    float* __restrict__ out) {
  __shared__ float aggbuf[64 * ASTR];     // 33792 B
  __shared__ bf16_t P_lds[64 * EPAD];     // 17408 B; aliased by t1 in node phase

  const int tid  = threadIdx.x;
  const int wv   = tid >> 6;
  const int lane = tid & 63;
  const int l16  = lane & 15;
  const int quad = lane >> 4;
  const int g0   = blockIdx.x * 64;

  for (int i = tid; i < 64 * ASTR; i += 256) aggbuf[i] = 0.0f;
  // stage this block's 64 P rows into LDS (read once from global)
  for (int i = tid; i < 64 * 16; i += 256) {
    const int row = i >> 4, fo = (i & 15) * 8;
    const int gr = min(g0 + row, kN - 1);
    *(bf16x8*)&P_lds[row * EPAD + fo] = *(const bf16x8*)(P + (size_t)gr * kD + fo);
  }

  const int cnt = min(cursor[blockIdx.x * 16], kCap);
  const int sbase = blockIdx.x * kCap;
  __syncthreads();

  float b2v[8];
#pragma unroll
  for (int j = 0; j < 8; ++j) b2v[j] = eb2[j * 16 + l16];

  // ---- edge phase: 128-edge tiles, 32 edges per wave, slot+Q double-buffered ----
  const int ntiles = (cnt + 127) >> 7;

  int lr_c[2], co_c[2];
#pragma unroll
  for (int ms = 0; ms < 2; ++ms) {
    const int idx = wv * 32 + ms * 16 + l16;
    const int s = (idx < cnt) ? slot_lc[sbase + idx] : -1;
    lr_c[ms] = (s >= 0) ? (s >> 16) : -1;
    co_c[ms] = (s >= 0) ? (s & 0xFFFF) : 0;
  }
  bf16x8 q_c[2][4];
#pragma unroll
  for (int ms = 0; ms < 2; ++ms)
#pragma unroll
    for (int ks = 0; ks < 4; ++ks)
      q_c[ms][ks] = *(const bf16x8*)(Q + (size_t)co_c[ms] * kD + ks * 32 + quad * 8);

  for (int t = 0; t < ntiles; ++t) {
    // prefetch next tile's slots + Q
    int lr_n[2], co_n[2];
#pragma unroll
    for (int ms = 0; ms < 2; ++ms) {
      const int idx = (t + 1) * 128 + wv * 32 + ms * 16 + l16;
      const int s = (idx < cnt) ? slot_lc[sbase + idx] : -1;
      lr_n[ms] = (s >= 0) ? (s >> 16) : -1;
      co_n[ms] = (s >= 0) ? (s & 0xFFFF) : 0;
    }
    bf16x8 q_n[2][4];
#pragma unroll
    for (int ms = 0; ms < 2; ++ms)
#pragma unroll
      for (int ks = 0; ks < 4; ++ks)
        q_n[ms][ks] = *(const bf16x8*)(Q + (size_t)co_n[ms] * kD + ks * 32 + quad * 8);

    // A = silu(P_lds[lrow] + Q)
    bf16x8 af[2][4];
#pragma unroll
    for (int ms = 0; ms < 2; ++ms) {
      const int lrow = (lr_c[ms] >= 0) ? lr_c[ms] : 0;
#pragma unroll
      for (int ks = 0; ks < 4; ++ks) {
        const bf16x8 p = *(const bf16x8*)&P_lds[lrow * EPAD + ks * 32 + quad * 8];
        bf16x8 a;
#pragma unroll
        for (int u = 0; u < 8; ++u) a[u] = (bf16_t)silu_f((float)p[u] + (float)q_c[ms][ks][u]);
        af[ms][ks] = a;
      }
    }

    f32x4 acc[2][8];
#pragma unroll
    for (int ms = 0; ms < 2; ++ms)
#pragma unroll
      for (int j = 0; j < 8; ++j) acc[ms][j] = (f32x4){0.f, 0.f, 0.f, 0.f};

#pragma unroll
    for (int ks = 0; ks < 4; ++ks)
#pragma unroll
      for (int j = 0; j < 8; ++j) {
        const bf16x8 b = *(const bf16x8*)(W2T + (size_t)(j * 16 + l16) * kD + ks * 32 + quad * 8);
        acc[0][j] = mfma16(af[0][ks], b, acc[0][j]);
        acc[1][j] = mfma16(af[1][ks], b, acc[1][j]);
      }

    // epilogue: silu + LDS atomic scatter (rows unsorted within bucket)
#pragma unroll
    for (int ms = 0; ms < 2; ++ms) {
      int rows[4];
#pragma unroll
      for (int r = 0; r < 4; ++r) rows[r] = __shfl(lr_c[ms], quad * 4 + r, 64);
#pragma unroll
      for (int j = 0; j < 8; ++j) {
#pragma unroll
        for (int r = 0; r < 4; ++r) {
          if (rows[r] >= 0)
            atomicAdd(&aggbuf[rows[r] * ASTR + j * 16 + l16], silu_f(acc[ms][j][r] + b2v[j]));
        }
      }
    }

#pragma unroll
    for (int ms = 0; ms < 2; ++ms) {
      lr_c[ms] = lr_n[ms];
      co_c[ms] = co_n[ms];
#pragma unroll
      for (int ks = 0; ks < 4; ++ks) q_c[ms][ks] = q_n[ms][ks];
    }
  }
  __syncthreads();

  // ---- node phase: out = h + silu([h | agg] @ nW1 + nb1) @ nW2 + nb2 ----
  const int n0 = wv * 32 + l16;
  const int n1 = n0 + 16;
  const float b1v[2] = {nb1[n0], nb1[n1]};
  const float b2n[2] = {nb2[n0], nb2[n1]};

  f32x4 acc[4][2];
#pragma unroll
  for (int ms = 0; ms < 4; ++ms)
#pragma unroll
    for (int j = 0; j < 2; ++j) acc[ms][j] = (f32x4){0.f, 0.f, 0.f, 0.f};

#pragma unroll
  for (int ks = 0; ks < 8; ++ks) {
    const bf16_t* wp = nW1T + ks * 32 + quad * 8;
    const bf16x8 b0 = *(const bf16x8*)(wp + (size_t)n0 * 256);
    const bf16x8 bq = *(const bf16x8*)(wp + (size_t)n1 * 256);
#pragma unroll
    for (int ms = 0; ms < 4; ++ms) {
      bf16x8 a;
      if (ks < 4) {
        int node = g0 + ms * 16 + l16;
        node = node < kN ? node : kN - 1;
        a = *(const bf16x8*)(h_bf + (size_t)node * kD + ks * 32 + quad * 8);
      } else {
        const int lrow = ms * 16 + l16;
        const float* ap = &aggbuf[lrow * ASTR + (ks - 4) * 32 + quad * 8];
        const float4 f0 = *(const float4*)ap;
        const float4 f1 = *(const float4*)(ap + 4);
        a = (bf16x8){(bf16_t)f0.x, (bf16_t)f0.y, (bf16_t)f0.z, (bf16_t)f0.w,
                     (bf16_t)f1.x, (bf16_t)f1.y, (bf16_t)f1.z, (bf16_t)f1.w};
      }
      acc[ms][0] = mfma16(a, b0, acc[ms][0]);
      acc[ms][1] = mfma16(a, bq, acc[ms][1]);
    }
  }
  __syncthreads();  // aggbuf reads done; P_lds no longer needed -> alias t1

  bf16_t* t1 = (bf16_t*)P_lds;
#pragma unroll
  for (int ms = 0; ms < 4; ++ms)
#pragma unroll
    for (int j = 0; j < 2; ++j) {
      const int n = wv * 32 + j * 16 + l16;
#pragma unroll
      for (int r = 0; r < 4; ++r) {
        const int m = ms * 16 + quad * 4 + r;
        t1[m * EPAD + n] = (bf16_t)silu_f(acc[ms][j][r] + b1v[j]);
      }
    }
  __syncthreads();

  f32x4 acc2[4][2];
#pragma unroll
  for (int ms = 0; ms < 4; ++ms)
#pragma unroll
    for (int j = 0; j < 2; ++j) acc2[ms][j] = (f32x4){0.f, 0.f, 0.f, 0.f};
#pragma unroll
  for (int ks = 0; ks < 4; ++ks) {
    const bf16_t* wp = nW2T + ks * 32 + quad * 8;
    const bf16x8 b0 = *(const bf16x8*)(wp + (size_t)n0 * 128);
    const bf16x8 bq = *(const bf16x8*)(wp + (size_t)n1 * 128);
#pragma unroll
    for (int ms = 0; ms < 4; ++ms) {
      const bf16x8 a = *(const bf16x8*)&t1[(ms * 16 + l16) * EPAD + ks * 32 + quad * 8];
      acc2[ms][0] = mfma16(a, b0, acc2[ms][0]);
      acc2[ms][1] = mfma16(a, bq, acc2[ms][1]);
    }
  }

#pragma unroll
  for (int ms = 0; ms < 4; ++ms)
#pragma unroll
    for (int j = 0; j < 2; ++j) {
      const int n = wv * 32 + j * 16 + l16;
#pragma unroll
      for (int r = 0; r < 4; ++r) {
        const int node = g0 + ms * 16 + quad * 4 + r;
        if (node < kN) {
          const size_t o = (size_t)node * kD + n;
          out[o] = h[o] + acc2[ms][j][r] + b2n[j];
        }
      }
    }
}

// ---------------- launch ----------------
extern "C" void kernel_launch(void* const* d_in, const int* in_sizes, int n_in,
                              void* d_out, int out_size, void* d_ws, size_t ws_size,
                              hipStream_t stream) {
  const float* h   = (const float*)d_in[0];
  const int*   ei  = (const int*)d_in[1];
  const float* eW1 = (const float*)d_in[2];
  const float* eb1 = (const float*)d_in[3];
  const float* eW2 = (const float*)d_in[4];
  const float* eb2 = (const float*)d_in[5];
  const float* nW1 = (const float*)d_in[6];
  const float* nb1 = (const float*)d_in[7];
  const float* nW2 = (const float*)d_in[8];
  const float* nb2 = (const float*)d_in[9];
  float* out = (float*)d_out;

  char* ws = (char*)d_ws;
  size_t off = 0;
  auto alloc = [&](size_t bytes) {
    void* p = ws + off;
    off += (bytes + 255) & ~(size_t)255;
    return p;
  };
  bf16_t* h_bf    = (bf16_t*)alloc((size_t)kN * kD * 2);   // 12.8 MB
  bf16_t* W1T     = (bf16_t*)alloc(256 * 128 * 2);
  bf16_t* W2T     = (bf16_t*)alloc(128 * 128 * 2);
  bf16_t* nW1T    = (bf16_t*)alloc(256 * 128 * 2);
  bf16_t* nW2T    = (bf16_t*)alloc(128 * 128 * 2);
  bf16_t* P       = (bf16_t*)alloc((size_t)kN * kD * 2);   // 12.8 MB
  bf16_t* Q       = (bf16_t*)alloc((size_t)kN * kD * 2);   // 12.8 MB
  int*    cursor  = (int*)alloc((size_t)NBKT * 16 * 4);    // 50 KB, 64 B padded
  int*    slot_lc = (int*)alloc((size_t)NBKT * kCap * 4);  // 6.4 MB

  hipMemsetAsync(cursor, 0, (size_t)NBKT * 16 * 4, stream);
  prep_kernel<<<64, 256, 0, stream>>>(eW1, eW2, nW1, nW2, W1T, W2T, nW1T, nW2T);
  mega_kernel<<<BUCKET_BLOCKS + NBKT, 256, 0, stream>>>(h, ei, W1T, eb1,
                                                        h_bf, P, Q, cursor, slot_lc);
  fused_kernel<<<NBKT, 256, 0, stream>>>(P, Q, slot_lc, cursor, W2T, eb2,
                                         h_bf, h, nW1T, nW2T, nb1, nb2, out);
}

// Round 6
// 482.524 us; speedup vs baseline: 1.9608x; 1.9608x over previous
//
#include <hip/hip_runtime.h>
#include <hip/hip_bf16.h>

typedef __bf16 bf16_t;
typedef bf16_t bf16x8 __attribute__((ext_vector_type(8)));
typedef bf16_t bf16x4 __attribute__((ext_vector_type(4)));
typedef float  f32x4  __attribute__((ext_vector_type(4)));

constexpr int kN = 50000;   // nodes
constexpr int kE = 800000;  // edges
constexpr int kD = 128;     // D == H
constexpr int EPAD = 136;   // bf16 LDS row stride (t1)
constexpr int ASTR = 132;   // aggbuf LDS row stride (fp32)
constexpr int kCap = 2048;  // per-bucket slot capacity (mean 1024, sd ~32)
constexpr int NBKT = (kN + 63) / 64;  // 782 buckets == fused blocks
constexpr int BUCKET_BLOCKS = 512;

__device__ __forceinline__ f32x4 mfma16(bf16x8 a, bf16x8 b, f32x4 c) {
  return __builtin_amdgcn_mfma_f32_16x16x32_bf16(a, b, c, 0, 0, 0);
}
__device__ __forceinline__ float silu_f(float x) {
  return x / (1.0f + __expf(-x));
}

// ---------------- K1: weight transposes only ----------------
__global__ void prep_kernel(const float* __restrict__ eW1, const float* __restrict__ eW2,
                            const float* __restrict__ nW1, const float* __restrict__ nW2,
                            bf16_t* __restrict__ W1T, bf16_t* __restrict__ W2T,
                            bf16_t* __restrict__ nW1T, bf16_t* __restrict__ nW2T) {
  const int idx = blockIdx.x * blockDim.x + threadIdx.x;
  const int stride = gridDim.x * blockDim.x;
  for (int i = idx; i < 256 * 128; i += stride) {
    const int n = i >> 8, k = i & 255;  // W1T[n][k] = eW1[k][n]
    W1T[i]  = (bf16_t)eW1[k * 128 + n];
    nW1T[i] = (bf16_t)nW1[k * 128 + n];
  }
  for (int i = idx; i < 128 * 128; i += stride) {
    const int n = i >> 7, k = i & 127;
    W2T[i]  = (bf16_t)eW2[k * 128 + n];
    nW2T[i] = (bf16_t)nW2[k * 128 + n];
  }
}

// ---------------- K2: bucket binning (blocks < BUCKET_BLOCKS) + P/Q + h_bf (rest) ----------------
// P = h@eW1_top + eb1, Q = h@eW1_bot. Slot word = (lrow<<16)|col, lrow = row & 63.
__global__ __launch_bounds__(256, 2) void mega_kernel(
    const float* __restrict__ h, const int* __restrict__ ei,
    const bf16_t* __restrict__ W1T, const float* __restrict__ eb1,
    bf16_t* __restrict__ h_bf, bf16_t* __restrict__ P, bf16_t* __restrict__ Q,
    int* __restrict__ cursor, int* __restrict__ slot_lc) {
  __shared__ bf16_t t1[64 * EPAD];

  if (blockIdx.x < BUCKET_BLOCKS) {
    const int idx = blockIdx.x * blockDim.x + threadIdx.x;
    const int stride = BUCKET_BLOCKS * blockDim.x;
    for (int e = idx; e < kE; e += stride) {
      const int r = ei[e];
      const int c = ei[kE + e];
      const int b = r >> 6;
      const int pos = atomicAdd(&cursor[b * 16], 1);
      if (pos < kCap) slot_lc[b * kCap + pos] = ((r & 63) << 16) | c;
    }
    return;
  }

  const int tid  = threadIdx.x;
  const int wv   = tid >> 6;
  const int lane = tid & 63;
  const int l16  = lane & 15;
  const int quad = lane >> 4;
  const int n0 = wv * 32 + l16;
  const int n1 = n0 + 16;
  const float b1v[2] = {eb1[n0], eb1[n1]};
  const int tb = (blockIdx.x - BUCKET_BLOCKS) * 64;

  f32x4 accp[4][2], accq[4][2];
#pragma unroll
  for (int ms = 0; ms < 4; ++ms)
#pragma unroll
    for (int j = 0; j < 2; ++j) {
      accp[ms][j] = (f32x4){0.f, 0.f, 0.f, 0.f};
      accq[ms][j] = (f32x4){0.f, 0.f, 0.f, 0.f};
    }

#pragma unroll
  for (int ks = 0; ks < 4; ++ks) {
    const bf16_t* wp = W1T + ks * 32 + quad * 8;
    const bf16x8 bt0 = *(const bf16x8*)(wp + (size_t)n0 * 256);
    const bf16x8 bt1 = *(const bf16x8*)(wp + (size_t)n1 * 256);
    const bf16x8 bb0 = *(const bf16x8*)(wp + (size_t)n0 * 256 + 128);
    const bf16x8 bb1 = *(const bf16x8*)(wp + (size_t)n1 * 256 + 128);
#pragma unroll
    for (int ms = 0; ms < 4; ++ms) {
      int node = tb + ms * 16 + l16;
      node = node < kN ? node : kN - 1;
      const float* hp = h + (size_t)node * kD + ks * 32 + quad * 8;
      const float4 f0 = *(const float4*)hp;
      const float4 f1 = *(const float4*)(hp + 4);
      const bf16x8 a = {(bf16_t)f0.x, (bf16_t)f0.y, (bf16_t)f0.z, (bf16_t)f0.w,
                        (bf16_t)f1.x, (bf16_t)f1.y, (bf16_t)f1.z, (bf16_t)f1.w};
      *(bf16x8*)(h_bf + (size_t)node * kD + ks * 32 + quad * 8) = a;  // dup-write benign
      accp[ms][0] = mfma16(a, bt0, accp[ms][0]);
      accp[ms][1] = mfma16(a, bt1, accp[ms][1]);
      accq[ms][0] = mfma16(a, bb0, accq[ms][0]);
      accq[ms][1] = mfma16(a, bb1, accq[ms][1]);
    }
  }

#pragma unroll
  for (int ms = 0; ms < 4; ++ms)
#pragma unroll
    for (int j = 0; j < 2; ++j) {
      const int n = wv * 32 + j * 16 + l16;
#pragma unroll
      for (int r = 0; r < 4; ++r)
        t1[(ms * 16 + quad * 4 + r) * EPAD + n] = (bf16_t)(accp[ms][j][r] + b1v[j]);
    }
  __syncthreads();
  {
    const int row = tid >> 2, cc = (tid & 3) * 32;
    const int node = tb + row;
    if (node < kN) {
#pragma unroll
      for (int u = 0; u < 4; ++u)
        *(bf16x8*)(P + (size_t)node * kD + cc + u * 8) = *(const bf16x8*)&t1[row * EPAD + cc + u * 8];
    }
  }
  __syncthreads();
#pragma unroll
  for (int ms = 0; ms < 4; ++ms)
#pragma unroll
    for (int j = 0; j < 2; ++j) {
      const int n = wv * 32 + j * 16 + l16;
#pragma unroll
      for (int r = 0; r < 4; ++r)
        t1[(ms * 16 + quad * 4 + r) * EPAD + n] = (bf16_t)accq[ms][j][r];
    }
  __syncthreads();
  {
    const int row = tid >> 2, cc = (tid & 3) * 32;
    const int node = tb + row;
    if (node < kN) {
#pragma unroll
      for (int u = 0; u < 4; ++u)
        *(bf16x8*)(Q + (size_t)node * kD + cc + u * 8) = *(const bf16x8*)&t1[row * EPAD + cc + u * 8];
    }
  }
}

// ---------------- K3: fused: LDS counting-sort -> edge MLP -> LDS aggregate -> node MLP ----------------
// Block b owns nodes [b*64, b*64+64) and slot bucket b. No global atomics.
__global__ __launch_bounds__(256, 3) void fused_kernel(
    const bf16_t* __restrict__ P, const bf16_t* __restrict__ Q,
    const int* __restrict__ slot_lc, const int* __restrict__ cursor,
    const bf16_t* __restrict__ W2T, const float* __restrict__ eb2,
    const bf16_t* __restrict__ h_bf, const float* __restrict__ h,
    const bf16_t* __restrict__ nW1T, const bf16_t* __restrict__ nW2T,
    const float* __restrict__ nb1, const float* __restrict__ nb2,
    float* __restrict__ out) {
  __shared__ float aggbuf[64 * ASTR];   // 33792 B; aliased by t1 (17408 B) in node phase
  __shared__ int  sorted[kCap];         // 8192 B: bucket slots, row-grouped
  __shared__ int  s_bin[64];            // hist -> cursor

  const int tid  = threadIdx.x;
  const int wv   = tid >> 6;
  const int lane = tid & 63;
  const int l16  = lane & 15;
  const int quad = lane >> 4;
  const int g0   = blockIdx.x * 64;

  for (int i = tid; i < 64 * ASTR; i += 256) aggbuf[i] = 0.0f;
  if (tid < 64) s_bin[tid] = 0;
  const int cnt = min(cursor[blockIdx.x * 16], kCap);
  const int sbase = blockIdx.x * kCap;
  __syncthreads();

  // ---- counting sort by lrow (order within row irrelevant) ----
  for (int i = tid; i < cnt; i += 256) atomicAdd(&s_bin[slot_lc[sbase + i] >> 16], 1);
  __syncthreads();
  if (tid == 0) {
    int run = 0;
#pragma unroll
    for (int r = 0; r < 64; ++r) {
      const int c = s_bin[r];
      s_bin[r] = run;
      run += c;
    }
  }
  __syncthreads();
  for (int i = tid; i < cnt; i += 256) {
    const int w = slot_lc[sbase + i];
    sorted[atomicAdd(&s_bin[w >> 16], 1)] = w;
  }
  __syncthreads();

  float b2v[8];
#pragma unroll
  for (int j = 0; j < 8; ++j) b2v[j] = eb2[j * 16 + l16];

  // ---- edge phase: 128-edge tiles, 32 edges per wave (2 m-slices) ----
  const int ntiles = (cnt + 127) >> 7;
  for (int t = 0; t < ntiles; ++t) {
    const int base = t * 128 + wv * 32;

    int lr[2];
    bf16x8 af[2][4];
#pragma unroll
    for (int ms = 0; ms < 2; ++ms) {
      const int idx = base + ms * 16 + l16;
      const int w = (idx < cnt) ? sorted[idx] : -1;
      lr[ms] = (w >= 0) ? (w >> 16) : -1;
      const int cn = (w >= 0) ? (w & 0xFFFF) : 0;
      const int pr = (w >= 0) ? (g0 + lr[ms]) : g0;
#pragma unroll
      for (int ks = 0; ks < 4; ++ks) {
        const bf16x8 p = *(const bf16x8*)(P + (size_t)pr * kD + ks * 32 + quad * 8);
        const bf16x8 q = *(const bf16x8*)(Q + (size_t)cn * kD + ks * 32 + quad * 8);
        bf16x8 a;
#pragma unroll
        for (int u = 0; u < 8; ++u) a[u] = (bf16_t)silu_f((float)p[u] + (float)q[u]);
        af[ms][ks] = a;
      }
    }

    f32x4 acc[2][8];
#pragma unroll
    for (int ms = 0; ms < 2; ++ms)
#pragma unroll
      for (int j = 0; j < 8; ++j) acc[ms][j] = (f32x4){0.f, 0.f, 0.f, 0.f};

#pragma unroll
    for (int ks = 0; ks < 4; ++ks)
#pragma unroll
      for (int j = 0; j < 8; ++j) {
        const bf16x8 b = *(const bf16x8*)(W2T + (size_t)(j * 16 + l16) * kD + ks * 32 + quad * 8);
        acc[0][j] = mfma16(af[0][ks], b, acc[0][j]);
        acc[1][j] = mfma16(af[1][ks], b, acc[1][j]);
      }

    // epilogue: silu + run-merged LDS atomic scatter (rows grouped by sort)
#pragma unroll
    for (int ms = 0; ms < 2; ++ms) {
      int rows[4];
#pragma unroll
      for (int r = 0; r < 4; ++r) rows[r] = __shfl(lr[ms], quad * 4 + r, 64);
#pragma unroll
      for (int j = 0; j < 8; ++j) {
        const int cbase = j * 16 + l16;
        float run = silu_f(acc[ms][j][0] + b2v[j]);
        int cur = rows[0];
#pragma unroll
        for (int r = 1; r < 4; ++r) {
          const float v = silu_f(acc[ms][j][r] + b2v[j]);
          if (rows[r] == cur) {
            run += v;
          } else {
            if (cur >= 0) atomicAdd(&aggbuf[cur * ASTR + cbase], run);
            cur = rows[r];
            run = v;
          }
        }
        if (cur >= 0) atomicAdd(&aggbuf[cur * ASTR + cbase], run);
      }
    }
  }
  __syncthreads();

  // ---- node phase: out = h + silu([h | agg] @ nW1 + nb1) @ nW2 + nb2 ----
  const int n0 = wv * 32 + l16;
  const int n1 = n0 + 16;
  const float b1v[2] = {nb1[n0], nb1[n1]};
  const float b2n[2] = {nb2[n0], nb2[n1]};

  f32x4 acc[4][2];
#pragma unroll
  for (int ms = 0; ms < 4; ++ms)
#pragma unroll
    for (int j = 0; j < 2; ++j) acc[ms][j] = (f32x4){0.f, 0.f, 0.f, 0.f};

#pragma unroll
  for (int ks = 0; ks < 8; ++ks) {
    const bf16_t* wp = nW1T + ks * 32 + quad * 8;
    const bf16x8 b0 = *(const bf16x8*)(wp + (size_t)n0 * 256);
    const bf16x8 bq = *(const bf16x8*)(wp + (size_t)n1 * 256);
#pragma unroll
    for (int ms = 0; ms < 4; ++ms) {
      bf16x8 a;
      if (ks < 4) {
        int node = g0 + ms * 16 + l16;
        node = node < kN ? node : kN - 1;
        a = *(const bf16x8*)(h_bf + (size_t)node * kD + ks * 32 + quad * 8);
      } else {
        const int lrow = ms * 16 + l16;
        const float* ap = &aggbuf[lrow * ASTR + (ks - 4) * 32 + quad * 8];
        const float4 f0 = *(const float4*)ap;
        const float4 f1 = *(const float4*)(ap + 4);
        a = (bf16x8){(bf16_t)f0.x, (bf16_t)f0.y, (bf16_t)f0.z, (bf16_t)f0.w,
                     (bf16_t)f1.x, (bf16_t)f1.y, (bf16_t)f1.z, (bf16_t)f1.w};
      }
      acc[ms][0] = mfma16(a, b0, acc[ms][0]);
      acc[ms][1] = mfma16(a, bq, acc[ms][1]);
    }
  }
  __syncthreads();  // aggbuf reads done -> alias t1

  bf16_t* t1 = (bf16_t*)aggbuf;
#pragma unroll
  for (int ms = 0; ms < 4; ++ms)
#pragma unroll
    for (int j = 0; j < 2; ++j) {
      const int n = wv * 32 + j * 16 + l16;
#pragma unroll
      for (int r = 0; r < 4; ++r) {
        const int m = ms * 16 + quad * 4 + r;
        t1[m * EPAD + n] = (bf16_t)silu_f(acc[ms][j][r] + b1v[j]);
      }
    }
  __syncthreads();

  f32x4 acc2[4][2];
#pragma unroll
  for (int ms = 0; ms < 4; ++ms)
#pragma unroll
    for (int j = 0; j < 2; ++j) acc2[ms][j] = (f32x4){0.f, 0.f, 0.f, 0.f};
#pragma unroll
  for (int ks = 0; ks < 4; ++ks) {
    const bf16_t* wp = nW2T + ks * 32 + quad * 8;
    const bf16x8 b0 = *(const bf16x8*)(wp + (size_t)n0 * 128);
    const bf16x8 bq = *(const bf16x8*)(wp + (size_t)n1 * 128);
#pragma unroll
    for (int ms = 0; ms < 4; ++ms) {
      const bf16x8 a = *(const bf16x8*)&t1[(ms * 16 + l16) * EPAD + ks * 32 + quad * 8];
      acc2[ms][0] = mfma16(a, b0, acc2[ms][0]);
      acc2[ms][1] = mfma16(a, bq, acc2[ms][1]);
    }
  }

#pragma unroll
  for (int ms = 0; ms < 4; ++ms)
#pragma unroll
    for (int j = 0; j < 2; ++j) {
      const int n = wv * 32 + j * 16 + l16;
#pragma unroll
      for (int r = 0; r < 4; ++r) {
        const int node = g0 + ms * 16 + quad * 4 + r;
        if (node < kN) {
          const size_t o = (size_t)node * kD + n;
          out[o] = h[o] + acc2[ms][j][r] + b2n[j];
        }
      }
    }
}

// ---------------- launch ----------------
extern "C" void kernel_launch(void* const* d_in, const int* in_sizes, int n_in,
                              void* d_out, int out_size, void* d_ws, size_t ws_size,
                              hipStream_t stream) {
  const float* h   = (const float*)d_in[0];
  const int*   ei  = (const int*)d_in[1];
  const float* eW1 = (const float*)d_in[2];
  const float* eb1 = (const float*)d_in[3];
  const float* eW2 = (const float*)d_in[4];
  const float* eb2 = (const float*)d_in[5];
  const float* nW1 = (const float*)d_in[6];
  const float* nb1 = (const float*)d_in[7];
  const float* nW2 = (const float*)d_in[8];
  const float* nb2 = (const float*)d_in[9];
  float* out = (float*)d_out;

  char* ws = (char*)d_ws;
  size_t off = 0;
  auto alloc = [&](size_t bytes) {
    void* p = ws + off;
    off += (bytes + 255) & ~(size_t)255;
    return p;
  };
  bf16_t* h_bf    = (bf16_t*)alloc((size_t)kN * kD * 2);   // 12.8 MB
  bf16_t* W1T     = (bf16_t*)alloc(256 * 128 * 2);
  bf16_t* W2T     = (bf16_t*)alloc(128 * 128 * 2);
  bf16_t* nW1T    = (bf16_t*)alloc(256 * 128 * 2);
  bf16_t* nW2T    = (bf16_t*)alloc(128 * 128 * 2);
  bf16_t* P       = (bf16_t*)alloc((size_t)kN * kD * 2);   // 12.8 MB
  bf16_t* Q       = (bf16_t*)alloc((size_t)kN * kD * 2);   // 12.8 MB
  int*    cursor  = (int*)alloc((size_t)NBKT * 16 * 4);    // 50 KB, 64 B padded
  int*    slot_lc = (int*)alloc((size_t)NBKT * kCap * 4);  // 6.4 MB

  hipMemsetAsync(cursor, 0, (size_t)NBKT * 16 * 4, stream);
  prep_kernel<<<64, 256, 0, stream>>>(eW1, eW2, nW1, nW2, W1T, W2T, nW1T, nW2T);
  mega_kernel<<<BUCKET_BLOCKS + NBKT, 256, 0, stream>>>(h, ei, W1T, eb1,
                                                        h_bf, P, Q, cursor, slot_lc);
  fused_kernel<<<NBKT, 256, 0, stream>>>(P, Q, slot_lc, cursor, W2T, eb2,
                                         h_bf, h, nW1T, nW2T, nb1, nb2, out);
}